// Round 10
// baseline (158.741 us; speedup 1.0000x reference)
//
#include <hip/hip_runtime.h>
#include <math.h>

#define S_ 6
#define N_ 10000
#define C_ 128
#define D_ 4
#define H_ 4
#define P_ 8
#define HF_ 28
#define WF_ 50
#define M_ (HF_ * WF_)   // 1400
#define DH_ 32
#define SM_ (S_ * M_)    // 8400
#define QB_ 8            // queries per attn block (256 threads)
// one fp8 value-copy: S*H*M pixels x 32 B = 1,075,200 B
#define ABYTES (S_ * H_ * M_ * 32)

#define NB_V ((SM_ + 31) / 32)   // 263 vproj blocks
#define NB_O ((N_ + 31) / 32)    // 313 OFFL blocks

typedef float floatx2 __attribute__((ext_vector_type(2)));
typedef _Float16 half4v __attribute__((ext_vector_type(4)));

// ---------------------------------------------------------------------------
// Shared GEMM body, K=128, MRx4 micro-tile, k-blocked by 4 with ds_read_b128.
//   MODE 0 (vproj): out = A@B0 + bias0 -> fp8 e4m3, DUAL layout:
//       copy A: ((s*H+h)*M + y*W + x)*32      (even-x pairs line-aligned)
//       copy B: ABYTES + (((s*H+h)*HF+y)*25 + (x-1)/2)*64 + (1-(x&1))*32
//   MODE 1 (OFFL):  out = (A+A2)@[B0|B1] + [bias0|bias1] -> fp32 (Mrows,96).
// ---------------------------------------------------------------------------
template <int NC, int MT, int MR, int MODE>
__device__ __forceinline__ void gemm_body(
    const float* __restrict__ A, const float* __restrict__ A2,
    const float* __restrict__ B0, const float* __restrict__ B1,
    const float* __restrict__ bias0, const float* __restrict__ bias1,
    float* __restrict__ outf, char* __restrict__ out8,
    int Mrows, int m0, int tid, int nthreads, float (*Alds)[132]) {
  constexpr int NTHR = (NC / 4) * (MT / MR);

  // ---- stage A tile (float4, coalesced), all block threads ---------------
  for (int i = tid; i < MT * 32; i += nthreads) {
    int r = i >> 5, k = (i & 31) * 4;
    int row = m0 + r;
    float4 v = make_float4(0.f, 0.f, 0.f, 0.f);
    if (row < Mrows) {
      v = *(const float4*)(A + (size_t)row * C_ + k);
      if (MODE == 1) {
        float4 v2 = *(const float4*)(A2 + (size_t)row * C_ + k);
        v.x += v2.x; v.y += v2.y; v.z += v2.z; v.w += v2.w;
      }
    }
    *(float4*)(&Alds[r][k]) = v;
  }
  __syncthreads();
  if (tid >= NTHR) return;  // no further barriers

  int ci = tid % (NC / 4);
  int mi = tid / (NC / 4);
  int c0 = ci * 4, r0 = mi * MR;

  const float* bs;
  if (MODE == 1) bs = (c0 < 64) ? bias0 + c0 : bias1 + (c0 - 64);
  else bs = bias0 + c0;

  float acc[MR][4];
#pragma unroll
  for (int j = 0; j < MR; ++j)
#pragma unroll
    for (int cc = 0; cc < 4; ++cc) acc[j][cc] = bs[cc];

#pragma unroll 2
  for (int k4 = 0; k4 < C_; k4 += 4) {
    float bf[16];
#pragma unroll
    for (int kk = 0; kk < 4; ++kk) {
      int k = k4 + kk;
      float4 b4;
      if (MODE == 1)
        b4 = (c0 < 64) ? *(const float4*)(B0 + (size_t)k * 64 + c0)
                       : *(const float4*)(B1 + (size_t)k * 32 + (c0 - 64));
      else
        b4 = *(const float4*)(B0 + (size_t)k * NC + c0);
      bf[kk * 4 + 0] = b4.x; bf[kk * 4 + 1] = b4.y;
      bf[kk * 4 + 2] = b4.z; bf[kk * 4 + 3] = b4.w;
    }
    float af[MR * 4];
#pragma unroll
    for (int j = 0; j < MR; ++j) {
      float4 a4 = *(const float4*)(&Alds[r0 + j][k4]);  // ds_read_b128
      af[j * 4 + 0] = a4.x; af[j * 4 + 1] = a4.y;
      af[j * 4 + 2] = a4.z; af[j * 4 + 3] = a4.w;
    }
#pragma unroll
    for (int j = 0; j < MR; ++j)
#pragma unroll
      for (int kk = 0; kk < 4; ++kk)
#pragma unroll
        for (int cc = 0; cc < 4; ++cc)
          acc[j][cc] = fmaf(af[j * 4 + kk], bf[kk * 4 + cc], acc[j][cc]);
  }

  // ---- epilogue ----------------------------------------------------------
#pragma unroll
  for (int j = 0; j < MR; ++j) {
    int row = m0 + r0 + j;
    if (row >= Mrows) continue;
    if (MODE == 0) {
      int s = row / M_, mm = row % M_;
      int y = mm / WF_, x = mm % WF_;
      int h = c0 >> 5, d0 = c0 & 31;
      int w = __builtin_amdgcn_cvt_pk_fp8_f32(acc[j][0], acc[j][1], 0, false);
      w = __builtin_amdgcn_cvt_pk_fp8_f32(acc[j][2], acc[j][3], w, true);
      size_t hm = (size_t)s * H_ + h;
      *(int*)(out8 + (hm * M_ + mm) * 32 + d0) = w;       // copy A
      if (x > 0) {                                        // copy B
        int kp = (x - 1) >> 1, slot = 1 - (x & 1);
        *(int*)(out8 + ABYTES + ((hm * HF_ + y) * 25 + kp) * 64 +
                slot * 32 + d0) = w;
      }
    } else if (MODE == 1) {
      *(float4*)(outf + (size_t)row * 96 + c0) =
          make_float4(acc[j][0], acc[j][1], acc[j][2], acc[j][3]);
    }
  }
}

// ---------------------------------------------------------------------------
__global__ __launch_bounds__(256) void prep_kernel(
    const float* __restrict__ value, const float* __restrict__ w_val,
    const float* __restrict__ b_val, char* __restrict__ vh8,
    const float* __restrict__ query, const float* __restrict__ query_pos,
    const float* __restrict__ w_off, const float* __restrict__ b_off,
    const float* __restrict__ w_attn, const float* __restrict__ b_attn,
    float* __restrict__ OFFL) {
  __shared__ float Alds[32][132];
  int bid = blockIdx.x;
  if (bid < NB_V) {
    gemm_body<128, 32, 4, 0>(value, nullptr, w_val, nullptr, b_val, nullptr,
                             nullptr, vh8, SM_, bid * 32, threadIdx.x, 256,
                             Alds);
  } else {
    gemm_body<96, 32, 4, 1>(query, query_pos, w_off, w_attn, b_off, b_attn,
                            OFFL, nullptr, N_, (bid - NB_V) * 32, threadIdx.x,
                            256, Alds);
  }
}

// ---------------------------------------------------------------------------
// Deformable sampling + tiled fused output projection. QB_=8 queries per
// 256-thread block. Gather: 32 threads/query; t: h=t>>3, c8=t&7; 8-lane
// group loads an x-adjacent pixel pair as ONE 64-B aligned span (parity-
// selected copy A/B -> exactly 2 cache lines/sample); shfl_xor(4) folds the
// pair; slot rows -> LDS. Out phase: 8 queries amortize each w_out row read
// (w_out L2 traffic = 64 KB/block, same as the separate 16-row out_kernel).
// ---------------------------------------------------------------------------
__global__ __launch_bounds__(256) void attn2_kernel(
    const float* __restrict__ OFFL,     // (N,96): [0:64)=off, [64:96)=logits
    const float* __restrict__ refpts,   // (S,1,N,D,2)
    const int*   __restrict__ bev_mask, // (S,1,N,D)
    const char*  __restrict__ vh8,      // dual fp8 layout, 64-B guard before
    const float* __restrict__ query,    // (N,128)
    const float* __restrict__ w_out,    // (128,128)
    const float* __restrict__ b_out,    // (128)
    float* __restrict__ out) {          // (N,128)
  int n0 = blockIdx.x * QB_;
  int tid = threadIdx.x;

  __shared__ float off[QB_][64];
  __shared__ float logits[QB_][32];
  __shared__ float aw[QB_][32];
  __shared__ float refl[QB_][48];
  __shared__ int smask[QB_][6];
  __shared__ int2 sidx[QB_][194];      // top/bottom span byte offsets
  __shared__ half4v swh[QB_][194];     // w00,w10,w01,w11 fp16 (pre-mult aw)
  __shared__ float sl[QB_][132];       // slot rows (pad +4)

  // ---- stage -------------------------------------------------------------
  for (int i = tid; i < QB_ * 96; i += 256) {
    int q = i / 96, c = i % 96;
    float v = OFFL[(size_t)(n0 + q) * 96 + c];
    if (c < 64) off[q][c] = v; else logits[q][c - 64] = v;
  }
  for (int i = tid; i < QB_ * 48; i += 256) {
    int q = i / 48, rem = i % 48;
    int s = rem >> 3, r8 = rem & 7;
    refl[q][rem] = refpts[((size_t)s * N_ + (n0 + q)) * 8 + r8];
  }
  if (tid < QB_ * 6) {
    int q = tid / 6, s = tid % 6;
    const int* bm = bev_mask + ((size_t)s * N_ + (n0 + q)) * D_;
    smask[q][s] = (bm[0] | bm[1] | bm[2] | bm[3]) ? 1 : 0;
  }
  __syncthreads();

  // ---- softmax over P per head: 256 threads = QB*32 exactly --------------
  {
    int q = tid >> 5, j = tid & 31, h = j >> 3;
    float mx = -1e30f;
#pragma unroll
    for (int p = 0; p < P_; ++p) mx = fmaxf(mx, logits[q][h * P_ + p]);
    float sum = 0.f;
#pragma unroll
    for (int p = 0; p < P_; ++p) sum += expf(logits[q][h * P_ + p] - mx);
    aw[q][j] = expf(logits[q][j] - mx) / sum;
  }
  __syncthreads();

  // ---- per-sample params: j = s*32 + p*4 + h -----------------------------
  for (int i = tid; i < QB_ * 192; i += 256) {
    int q = i / 192, j = i % 192;
    int s = j >> 5, w32 = j & 31, p = w32 >> 2, h = w32 & 3;
    int pd = p >> 2, dd = p & 3;
    float rx = refl[q][s * 8 + dd * 2 + 0];
    float ry = refl[q][s * 8 + dd * 2 + 1];
    float ox = off[q][h * 16 + pd * 8 + dd * 2 + 0];
    float oy = off[q][h * 16 + pd * 8 + dd * 2 + 1];
    float ix = rx * (float)WF_ + ox - 0.5f;
    float iy = ry * (float)HF_ + oy - 0.5f;
    float x0f = floorf(ix), y0f = floorf(iy);
    int x0 = (int)x0f, y0 = (int)y0f;
    float wx1 = ix - x0f, wy1 = iy - y0f;
    float wx0 = 1.f - wx1, wy0 = 1.f - wy1;
    float a = aw[q][h * P_ + p];
    bool vx0 = (x0 >= 0) && (x0 < WF_);
    bool vx1 = (x0 + 1 >= 0) && (x0 + 1 < WF_);
    bool vy0 = (y0 >= 0) && (y0 < HF_);
    bool vy1 = (y0 + 1 >= 0) && (y0 + 1 < HF_);
    int y0c = min(max(y0, 0), HF_ - 1);
    int y1c = min(max(y0 + 1, 0), HF_ - 1);
    int hm = s * H_ + h;
    int itop, ibot;
    if (x0 >= 0 && x0 <= WF_ - 2 && !(x0 & 1)) {
      itop = (hm * M_ + y0c * WF_ + x0) * 32;        // copy A, aligned
      ibot = (hm * M_ + y1c * WF_ + x0) * 32;
    } else if (x0 >= 1 && x0 <= WF_ - 1 && (x0 & 1)) {
      int kp = (x0 - 1) >> 1;                        // copy B, aligned
      itop = ABYTES + ((hm * HF_ + y0c) * 25 + kp) * 64;
      ibot = ABYTES + ((hm * HF_ + y1c) * 25 + kp) * 64;
    } else if (x0 == -1) {
      itop = (hm * M_ + y0c * WF_) * 32 - 32;        // guard-backed
      ibot = (hm * M_ + y1c * WF_) * 32 - 32;
    } else {
      itop = ibot = 0;  // all weights 0
    }
    float w00 = (vx0 && vy0) ? wx0 * wy0 * a : 0.f;
    float w10 = (vx1 && vy0) ? wx1 * wy0 * a : 0.f;
    float w01 = (vx0 && vy1) ? wx0 * wy1 * a : 0.f;
    float w11 = (vx1 && vy1) ? wx1 * wy1 * a : 0.f;
    sidx[q][j] = make_int2(itop, ibot);
    half4v wv = {(_Float16)w00, (_Float16)w10, (_Float16)w01, (_Float16)w11};
    swh[q][j] = wv;
  }
  __syncthreads();

  // ---- gather ------------------------------------------------------------
  {
    int q = tid >> 5, t = tid & 31, h = t >> 3, c8 = t & 7;
    bool hi = (c8 & 4) != 0;            // x0+1 half of the pair
    const char* vb = vh8 + c8 * 8;
    float av[8] = {0.f, 0.f, 0.f, 0.f, 0.f, 0.f, 0.f, 0.f};
    for (int s = 0; s < S_; ++s) {
      if (!smask[q][s]) continue;
#pragma unroll
      for (int p = 0; p < P_; ++p) {
        int j = s * 32 + p * 4 + h;
        int2 I = sidx[q][j];
        half4v W = swh[q][j];
        float wt = hi ? (float)W[1] : (float)W[0];
        float wb = hi ? (float)W[3] : (float)W[2];
        int2 ta = *(const int2*)(vb + I.x);
        int2 tb = *(const int2*)(vb + I.y);
        floatx2 t0 = __builtin_amdgcn_cvt_pk_f32_fp8(ta.x, false);
        floatx2 t1 = __builtin_amdgcn_cvt_pk_f32_fp8(ta.x, true);
        floatx2 t2 = __builtin_amdgcn_cvt_pk_f32_fp8(ta.y, false);
        floatx2 t3 = __builtin_amdgcn_cvt_pk_f32_fp8(ta.y, true);
        av[0] = fmaf(t0.x, wt, av[0]); av[1] = fmaf(t0.y, wt, av[1]);
        av[2] = fmaf(t1.x, wt, av[2]); av[3] = fmaf(t1.y, wt, av[3]);
        av[4] = fmaf(t2.x, wt, av[4]); av[5] = fmaf(t2.y, wt, av[5]);
        av[6] = fmaf(t3.x, wt, av[6]); av[7] = fmaf(t3.y, wt, av[7]);
        floatx2 b0 = __builtin_amdgcn_cvt_pk_f32_fp8(tb.x, false);
        floatx2 b1 = __builtin_amdgcn_cvt_pk_f32_fp8(tb.x, true);
        floatx2 b2 = __builtin_amdgcn_cvt_pk_f32_fp8(tb.y, false);
        floatx2 b3 = __builtin_amdgcn_cvt_pk_f32_fp8(tb.y, true);
        av[0] = fmaf(b0.x, wb, av[0]); av[1] = fmaf(b0.y, wb, av[1]);
        av[2] = fmaf(b1.x, wb, av[2]); av[3] = fmaf(b1.y, wb, av[3]);
        av[4] = fmaf(b2.x, wb, av[4]); av[5] = fmaf(b2.y, wb, av[5]);
        av[6] = fmaf(b3.x, wb, av[6]); av[7] = fmaf(b3.y, wb, av[7]);
      }
    }
    // fold x-pair halves: lanes c8 and c8^4 hold the same channels
#pragma unroll
    for (int k = 0; k < 8; ++k) av[k] += __shfl_xor(av[k], 4);

    if (!hi) {
      int cnt = smask[q][0] + smask[q][1] + smask[q][2] +
                smask[q][3] + smask[q][4] + smask[q][5];
      float inv = 1.f / (float)(cnt > 0 ? cnt : 1);
      float* dst = &sl[q][h * DH_ + (c8 & 3) * 8];
#pragma unroll
      for (int k = 0; k < 8; ++k) dst[k] = av[k] * inv;
    }
  }
  __syncthreads();

  // ---- tiled output projection: out = sl@w_out + b_out + query -----------
  {
    int q2 = tid >> 5, c0 = (tid & 31) * 4;
    int n = n0 + q2;
    float4 qv = *(const float4*)(query + (size_t)n * C_ + c0);
    float4 bv = *(const float4*)(b_out + c0);
    float r0 = bv.x + qv.x, r1 = bv.y + qv.y;
    float r2 = bv.z + qv.z, r3 = bv.w + qv.w;
#pragma unroll 4
    for (int k = 0; k < C_; ++k) {
      float a = sl[q2][k];
      float4 w4 = *(const float4*)(w_out + (size_t)k * C_ + c0);
      r0 = fmaf(a, w4.x, r0); r1 = fmaf(a, w4.y, r1);
      r2 = fmaf(a, w4.z, r2); r3 = fmaf(a, w4.w, r3);
    }
    *(float4*)(out + (size_t)n * C_ + c0) = make_float4(r0, r1, r2, r3);
  }
}

// ---------------------------------------------------------------------------
extern "C" void kernel_launch(void* const* d_in, const int* in_sizes, int n_in,
                              void* d_out, int out_size, void* d_ws, size_t ws_size,
                              hipStream_t stream) {
  const float* query     = (const float*)d_in[0];
  const float* value     = (const float*)d_in[2];
  const float* query_pos = (const float*)d_in[3];
  const float* refpts    = (const float*)d_in[4];
  const int*   bev_mask  = (const int*)d_in[5];
  const float* w_off     = (const float*)d_in[6];
  const float* b_off     = (const float*)d_in[7];
  const float* w_attn    = (const float*)d_in[8];
  const float* b_attn    = (const float*)d_in[9];
  const float* w_val     = (const float*)d_in[10];
  const float* b_val     = (const float*)d_in[11];
  const float* w_out     = (const float*)d_in[12];
  const float* b_out     = (const float*)d_in[13];

  char* ws = (char*)d_ws;
  char* vh8   = ws + 64;                   // dual copies: 2*ABYTES = 2,150,400
  float* OFFL = (float*)(ws + 64 + 2 * (size_t)ABYTES + 64);   // 3,840,000 B

  prep_kernel<<<NB_V + NB_O, 256, 0, stream>>>(
      value, w_val, b_val, vh8, query, query_pos, w_off, b_off, w_attn, b_attn,
      OFFL);
  attn2_kernel<<<N_ / QB_, 256, 0, stream>>>(OFFL, refpts, bev_mask, vh8,
                                             query, w_out, b_out,
                                             (float*)d_out);
}

// Round 11
// 156.041 us; speedup vs baseline: 1.0173x; 1.0173x over previous
//
#include <hip/hip_runtime.h>
#include <math.h>

#define S_ 6
#define N_ 10000
#define C_ 128
#define D_ 4
#define H_ 4
#define P_ 8
#define HF_ 28
#define WF_ 50
#define M_ (HF_ * WF_)   // 1400
#define DH_ 32
#define SM_ (S_ * M_)    // 8400
#define QB_ 8            // queries per attn block (256 threads)
// one fp8 value-copy: S*H*M pixels x 32 B = 1,075,200 B
#define ABYTES (S_ * H_ * M_ * 32)

#define NB_V ((SM_ + 31) / 32)   // 263 vproj blocks
#define NB_O ((N_ + 31) / 32)    // 313 OFFL blocks

typedef float floatx2 __attribute__((ext_vector_type(2)));
typedef _Float16 half2v __attribute__((ext_vector_type(2)));

// ---------------------------------------------------------------------------
// Shared GEMM body, K=128, MRx4 micro-tile, k-blocked by 4 with ds_read_b128.
//   MODE 0 (vproj): out = A@B0 + bias0 -> fp8 e4m3, DUAL layout (A/B parity).
//   MODE 1 (OFFL):  out = (A+A2)@[B0|B1] + [bias0|bias1] -> fp32 (Mrows,96).
// ---------------------------------------------------------------------------
template <int NC, int MT, int MR, int MODE>
__device__ __forceinline__ void gemm_body(
    const float* __restrict__ A, const float* __restrict__ A2,
    const float* __restrict__ B0, const float* __restrict__ B1,
    const float* __restrict__ bias0, const float* __restrict__ bias1,
    float* __restrict__ outf, char* __restrict__ out8,
    int Mrows, int m0, int tid, int nthreads, float (*Alds)[132]) {
  constexpr int NTHR = (NC / 4) * (MT / MR);

  for (int i = tid; i < MT * 32; i += nthreads) {
    int r = i >> 5, k = (i & 31) * 4;
    int row = m0 + r;
    float4 v = make_float4(0.f, 0.f, 0.f, 0.f);
    if (row < Mrows) {
      v = *(const float4*)(A + (size_t)row * C_ + k);
      if (MODE == 1) {
        float4 v2 = *(const float4*)(A2 + (size_t)row * C_ + k);
        v.x += v2.x; v.y += v2.y; v.z += v2.z; v.w += v2.w;
      }
    }
    *(float4*)(&Alds[r][k]) = v;
  }
  __syncthreads();
  if (tid >= NTHR) return;

  int ci = tid % (NC / 4);
  int mi = tid / (NC / 4);
  int c0 = ci * 4, r0 = mi * MR;

  const float* bs;
  if (MODE == 1) bs = (c0 < 64) ? bias0 + c0 : bias1 + (c0 - 64);
  else bs = bias0 + c0;

  float acc[MR][4];
#pragma unroll
  for (int j = 0; j < MR; ++j)
#pragma unroll
    for (int cc = 0; cc < 4; ++cc) acc[j][cc] = bs[cc];

#pragma unroll 2
  for (int k4 = 0; k4 < C_; k4 += 4) {
    float bf[16];
#pragma unroll
    for (int kk = 0; kk < 4; ++kk) {
      int k = k4 + kk;
      float4 b4;
      if (MODE == 1)
        b4 = (c0 < 64) ? *(const float4*)(B0 + (size_t)k * 64 + c0)
                       : *(const float4*)(B1 + (size_t)k * 32 + (c0 - 64));
      else
        b4 = *(const float4*)(B0 + (size_t)k * NC + c0);
      bf[kk * 4 + 0] = b4.x; bf[kk * 4 + 1] = b4.y;
      bf[kk * 4 + 2] = b4.z; bf[kk * 4 + 3] = b4.w;
    }
    float af[MR * 4];
#pragma unroll
    for (int j = 0; j < MR; ++j) {
      float4 a4 = *(const float4*)(&Alds[r0 + j][k4]);
      af[j * 4 + 0] = a4.x; af[j * 4 + 1] = a4.y;
      af[j * 4 + 2] = a4.z; af[j * 4 + 3] = a4.w;
    }
#pragma unroll
    for (int j = 0; j < MR; ++j)
#pragma unroll
      for (int kk = 0; kk < 4; ++kk)
#pragma unroll
        for (int cc = 0; cc < 4; ++cc)
          acc[j][cc] = fmaf(af[j * 4 + kk], bf[kk * 4 + cc], acc[j][cc]);
  }

#pragma unroll
  for (int j = 0; j < MR; ++j) {
    int row = m0 + r0 + j;
    if (row >= Mrows) continue;
    if (MODE == 0) {
      int s = row / M_, mm = row % M_;
      int y = mm / WF_, x = mm % WF_;
      int h = c0 >> 5, d0 = c0 & 31;
      int w = __builtin_amdgcn_cvt_pk_fp8_f32(acc[j][0], acc[j][1], 0, false);
      w = __builtin_amdgcn_cvt_pk_fp8_f32(acc[j][2], acc[j][3], w, true);
      size_t hm = (size_t)s * H_ + h;
      *(int*)(out8 + (hm * M_ + mm) * 32 + d0) = w;       // copy A
      if (x > 0) {                                        // copy B
        int kp = (x - 1) >> 1, slot = 1 - (x & 1);
        *(int*)(out8 + ABYTES + ((hm * HF_ + y) * 25 + kp) * 64 +
                slot * 32 + d0) = w;
      }
    } else if (MODE == 1) {
      *(float4*)(outf + (size_t)row * 96 + c0) =
          make_float4(acc[j][0], acc[j][1], acc[j][2], acc[j][3]);
    }
  }
}

// ---------------------------------------------------------------------------
__global__ __launch_bounds__(256) void prep_kernel(
    const float* __restrict__ value, const float* __restrict__ w_val,
    const float* __restrict__ b_val, char* __restrict__ vh8,
    const float* __restrict__ query, const float* __restrict__ query_pos,
    const float* __restrict__ w_off, const float* __restrict__ b_off,
    const float* __restrict__ w_attn, const float* __restrict__ b_attn,
    float* __restrict__ OFFL) {
  __shared__ float Alds[32][132];
  int bid = blockIdx.x;
  if (bid < NB_V) {
    gemm_body<128, 32, 4, 0>(value, nullptr, w_val, nullptr, b_val, nullptr,
                             nullptr, vh8, SM_, bid * 32, threadIdx.x, 256,
                             Alds);
  } else {
    gemm_body<96, 32, 4, 1>(query, query_pos, w_off, w_attn, b_off, b_attn,
                            OFFL, nullptr, N_, (bid - NB_V) * 32, threadIdx.x,
                            256, Alds);
  }
}

// ---------------------------------------------------------------------------
// Fused deformable sampling + output projection. QB_=8 queries / 256 threads.
// LDS budget ~30.7 KB (5 blocks/CU): sl overlays the dead stage arrays.
// Gather: branch-free 48-sample loop (smask folded into weights); per sample:
// 1 ds_read_b64 (idx pair) + 1 ds_read_b32 (fp16x2 weight word picked by
// x-half) + 2 saddr-form dwordx2 loads (pre-biased 32-bit offsets).
// ---------------------------------------------------------------------------
__global__ __launch_bounds__(256) void attn2_kernel(
    const float* __restrict__ OFFL,     // (N,96): [0:64)=off, [64:96)=logits
    const float* __restrict__ refpts,   // (S,1,N,D,2)
    const int*   __restrict__ bev_mask, // (S,1,N,D)
    const char*  __restrict__ wsbase,   // d_ws base; value data at +64 (dual)
    const float* __restrict__ query,    // (N,128)
    const float* __restrict__ w_out,    // (128,128)
    const float* __restrict__ b_out,    // (128)
    float* __restrict__ out) {          // (N,128)
  int n0 = blockIdx.x * QB_;
  int tid = threadIdx.x;

  // ---- manual LDS layout (31 KB) -----------------------------------------
  __shared__ char smem[30656];
  int2*   sidx  = (int2*)smem;                       // [q*194+j] 12416 B
  half2v* swh   = (half2v*)(smem + 12416);           // [(q*194+j)*2+half] 12416 B
  float*  offp  = (float*)(smem + 24832);            // [q*64+c]  2048 B
  float*  logtp = (float*)(smem + 24832 + 2048);     // [q*32+j]  1024 B
  float*  awp   = (float*)(smem + 24832 + 3072);     // [q*32+j]  1024 B
  float*  reflp = (float*)(smem + 24832 + 4096);     // [q*48+r]  1536 B
  float*  slp   = (float*)(smem + 24832);            // [q*132+k] overlays stage
  int*    smaskp= (int*)(smem + 30464);              // [q*6+s]   192 B

  // ---- stage -------------------------------------------------------------
  for (int i = tid; i < QB_ * 96; i += 256) {
    int q = i / 96, c = i % 96;
    float v = OFFL[(size_t)(n0 + q) * 96 + c];
    if (c < 64) offp[q * 64 + c] = v; else logtp[q * 32 + c - 64] = v;
  }
  for (int i = tid; i < QB_ * 48; i += 256) {
    int q = i / 48, rem = i % 48;
    int s = rem >> 3, r8 = rem & 7;
    reflp[q * 48 + rem] = refpts[((size_t)s * N_ + (n0 + q)) * 8 + r8];
  }
  if (tid < QB_ * 6) {
    int q = tid / 6, s = tid % 6;
    const int* bm = bev_mask + ((size_t)s * N_ + (n0 + q)) * D_;
    smaskp[tid] = (bm[0] | bm[1] | bm[2] | bm[3]) ? 1 : 0;
  }
  __syncthreads();

  // ---- softmax over P per head: 256 threads = QB*32 exactly --------------
  {
    int q = tid >> 5, j = tid & 31, h = j >> 3;
    float mx = -1e30f;
#pragma unroll
    for (int p = 0; p < P_; ++p) mx = fmaxf(mx, logtp[q * 32 + h * P_ + p]);
    float sum = 0.f;
#pragma unroll
    for (int p = 0; p < P_; ++p) sum += expf(logtp[q * 32 + h * P_ + p] - mx);
    awp[q * 32 + j] = expf(logtp[q * 32 + j] - mx) / sum;
  }
  __syncthreads();

  // ---- per-sample params: j = s*32 + p*4 + h; smask folded into weights --
  for (int i = tid; i < QB_ * 192; i += 256) {
    int q = i / 192, j = i % 192;
    int s = j >> 5, w32 = j & 31, p = w32 >> 2, h = w32 & 3;
    int pd = p >> 2, dd = p & 3;
    float rx = reflp[q * 48 + s * 8 + dd * 2 + 0];
    float ry = reflp[q * 48 + s * 8 + dd * 2 + 1];
    float ox = offp[q * 64 + h * 16 + pd * 8 + dd * 2 + 0];
    float oy = offp[q * 64 + h * 16 + pd * 8 + dd * 2 + 1];
    float ix = rx * (float)WF_ + ox - 0.5f;
    float iy = ry * (float)HF_ + oy - 0.5f;
    float x0f = floorf(ix), y0f = floorf(iy);
    int x0 = (int)x0f, y0 = (int)y0f;
    float wx1 = ix - x0f, wy1 = iy - y0f;
    float wx0 = 1.f - wx1, wy0 = 1.f - wy1;
    float a = awp[q * 32 + h * P_ + p] * (float)smaskp[q * 6 + s];
    bool vx0 = (x0 >= 0) && (x0 < WF_);
    bool vx1 = (x0 + 1 >= 0) && (x0 + 1 < WF_);
    bool vy0 = (y0 >= 0) && (y0 < HF_);
    bool vy1 = (y0 + 1 >= 0) && (y0 + 1 < HF_);
    int y0c = min(max(y0, 0), HF_ - 1);
    int y1c = min(max(y0 + 1, 0), HF_ - 1);
    int hm = s * H_ + h;
    int itop, ibot;
    if (x0 >= 0 && x0 <= WF_ - 2 && !(x0 & 1)) {
      itop = (hm * M_ + y0c * WF_ + x0) * 32;        // copy A, aligned
      ibot = (hm * M_ + y1c * WF_ + x0) * 32;
    } else if (x0 >= 1 && x0 <= WF_ - 1 && (x0 & 1)) {
      int kp = (x0 - 1) >> 1;                        // copy B, aligned
      itop = ABYTES + ((hm * HF_ + y0c) * 25 + kp) * 64;
      ibot = ABYTES + ((hm * HF_ + y1c) * 25 + kp) * 64;
    } else if (x0 == -1) {
      itop = (hm * M_ + y0c * WF_) * 32 - 32;        // guard-backed
      ibot = (hm * M_ + y1c * WF_) * 32 - 32;
    } else {
      itop = ibot = 0;  // all weights 0
    }
    float w00 = (vx0 && vy0) ? wx0 * wy0 * a : 0.f;
    float w10 = (vx1 && vy0) ? wx1 * wy0 * a : 0.f;
    float w01 = (vx0 && vy1) ? wx0 * wy1 * a : 0.f;
    float w11 = (vx1 && vy1) ? wx1 * wy1 * a : 0.f;
    // +64 bias: offsets are relative to d_ws base (all non-negative)
    sidx[q * 194 + j] = make_int2(itop + 64, ibot + 64);
    half2v lo = {(_Float16)w00, (_Float16)w01};  // x0 half: (top, bottom)
    half2v hi = {(_Float16)w10, (_Float16)w11};  // x0+1 half
    swh[(q * 194 + j) * 2 + 0] = lo;
    swh[(q * 194 + j) * 2 + 1] = hi;
  }
  __syncthreads();

  // ---- gather: branch-free 48-sample loop --------------------------------
  {
    int q = tid >> 5, t = tid & 31, h = t >> 3, c8 = t & 7;
    int hisel = (c8 >> 2) & 1;          // which x-half this lane holds
    int lanebyte = c8 * 8;
    const int2* sx = sidx + q * 194;
    const half2v* swq = swh + (q * 194) * 2 + hisel;
    float av[8] = {0.f, 0.f, 0.f, 0.f, 0.f, 0.f, 0.f, 0.f};
#pragma unroll 4
    for (int u = 0; u < 48; ++u) {
      int j = (u >> 3) * 32 + (u & 7) * 4 + h;
      int2 I = sx[j];
      half2v w2 = swq[j * 2];
      float wt = (float)w2[0], wb = (float)w2[1];
      int2 ta = *(const int2*)(wsbase + (I.x + lanebyte));
      int2 tb = *(const int2*)(wsbase + (I.y + lanebyte));
      floatx2 t0 = __builtin_amdgcn_cvt_pk_f32_fp8(ta.x, false);
      floatx2 t1 = __builtin_amdgcn_cvt_pk_f32_fp8(ta.x, true);
      floatx2 t2 = __builtin_amdgcn_cvt_pk_f32_fp8(ta.y, false);
      floatx2 t3 = __builtin_amdgcn_cvt_pk_f32_fp8(ta.y, true);
      av[0] = fmaf(t0.x, wt, av[0]); av[1] = fmaf(t0.y, wt, av[1]);
      av[2] = fmaf(t1.x, wt, av[2]); av[3] = fmaf(t1.y, wt, av[3]);
      av[4] = fmaf(t2.x, wt, av[4]); av[5] = fmaf(t2.y, wt, av[5]);
      av[6] = fmaf(t3.x, wt, av[6]); av[7] = fmaf(t3.y, wt, av[7]);
      floatx2 b0 = __builtin_amdgcn_cvt_pk_f32_fp8(tb.x, false);
      floatx2 b1 = __builtin_amdgcn_cvt_pk_f32_fp8(tb.x, true);
      floatx2 b2 = __builtin_amdgcn_cvt_pk_f32_fp8(tb.y, false);
      floatx2 b3 = __builtin_amdgcn_cvt_pk_f32_fp8(tb.y, true);
      av[0] = fmaf(b0.x, wb, av[0]); av[1] = fmaf(b0.y, wb, av[1]);
      av[2] = fmaf(b1.x, wb, av[2]); av[3] = fmaf(b1.y, wb, av[3]);
      av[4] = fmaf(b2.x, wb, av[4]); av[5] = fmaf(b2.y, wb, av[5]);
      av[6] = fmaf(b3.x, wb, av[6]); av[7] = fmaf(b3.y, wb, av[7]);
    }
    // fold x-pair halves: lanes c8 and c8^4 hold the same channels
#pragma unroll
    for (int k = 0; k < 8; ++k) av[k] += __shfl_xor(av[k], 4);

    int cnt = smaskp[q * 6 + 0] + smaskp[q * 6 + 1] + smaskp[q * 6 + 2] +
              smaskp[q * 6 + 3] + smaskp[q * 6 + 4] + smaskp[q * 6 + 5];
    float inv = 1.f / (float)(cnt > 0 ? cnt : 1);
    __syncthreads();  // all reads of sidx/swh done before sl overlay write
    if (!hisel) {
      float* dst = &slp[q * 132 + h * DH_ + (c8 & 3) * 8];
#pragma unroll
      for (int k = 0; k < 8; ++k) dst[k] = av[k] * inv;
    }
  }
  __syncthreads();

  // ---- tiled output projection: out = sl@w_out + b_out + query -----------
  {
    int q2 = tid >> 5, c0 = (tid & 31) * 4;
    int n = n0 + q2;
    float4 qv = *(const float4*)(query + (size_t)n * C_ + c0);
    float4 bv = *(const float4*)(b_out + c0);
    float r0 = bv.x + qv.x, r1 = bv.y + qv.y;
    float r2 = bv.z + qv.z, r3 = bv.w + qv.w;
#pragma unroll 4
    for (int k = 0; k < C_; ++k) {
      float a = slp[q2 * 132 + k];
      float4 w4 = *(const float4*)(w_out + (size_t)k * C_ + c0);
      r0 = fmaf(a, w4.x, r0); r1 = fmaf(a, w4.y, r1);
      r2 = fmaf(a, w4.z, r2); r3 = fmaf(a, w4.w, r3);
    }
    *(float4*)(out + (size_t)n * C_ + c0) = make_float4(r0, r1, r2, r3);
  }
}

// ---------------------------------------------------------------------------
extern "C" void kernel_launch(void* const* d_in, const int* in_sizes, int n_in,
                              void* d_out, int out_size, void* d_ws, size_t ws_size,
                              hipStream_t stream) {
  const float* query     = (const float*)d_in[0];
  const float* value     = (const float*)d_in[2];
  const float* query_pos = (const float*)d_in[3];
  const float* refpts    = (const float*)d_in[4];
  const int*   bev_mask  = (const int*)d_in[5];
  const float* w_off     = (const float*)d_in[6];
  const float* b_off     = (const float*)d_in[7];
  const float* w_attn    = (const float*)d_in[8];
  const float* b_attn    = (const float*)d_in[9];
  const float* w_val     = (const float*)d_in[10];
  const float* b_val     = (const float*)d_in[11];
  const float* w_out     = (const float*)d_in[12];
  const float* b_out     = (const float*)d_in[13];

  char* ws = (char*)d_ws;
  char* vh8   = ws + 64;                   // dual copies: 2*ABYTES = 2,150,400
  float* OFFL = (float*)(ws + 64 + 2 * (size_t)ABYTES + 64);   // 3,840,000 B

  prep_kernel<<<NB_V + NB_O, 256, 0, stream>>>(
      value, w_val, b_val, vh8, query, query_pos, w_off, b_off, w_attn, b_attn,
      OFFL);
  attn2_kernel<<<N_ / QB_, 256, 0, stream>>>(OFFL, refpts, bev_mask, ws,
                                             query, w_out, b_out,
                                             (float*)d_out);
}

// Round 12
// 154.841 us; speedup vs baseline: 1.0252x; 1.0077x over previous
//
#include <hip/hip_runtime.h>
#include <math.h>

#define S_ 6
#define N_ 10000
#define C_ 128
#define D_ 4
#define H_ 4
#define P_ 8
#define HF_ 28
#define WF_ 50
#define M_ (HF_ * WF_)   // 1400
#define DH_ 32
#define SM_ (S_ * M_)    // 8400
#define QB_ 8            // queries per attn block (256 threads)
// one fp8 value-copy: S*H*M pixels x 32 B = 1,075,200 B
#define ABYTES (S_ * H_ * M_ * 32)

#define NB_V ((SM_ + 31) / 32)   // 263 vproj blocks
#define NB_O ((N_ + 31) / 32)    // 313 OFFL blocks

typedef float floatx2 __attribute__((ext_vector_type(2)));
typedef _Float16 half2v __attribute__((ext_vector_type(2)));

// ---------------------------------------------------------------------------
// Shared GEMM body, K=128, MRx4 micro-tile, k-blocked by 4 with ds_read_b128.
//   MODE 0 (vproj): out = A@B0 + bias0 -> fp8 e4m3, DUAL layout (A/B parity).
//   MODE 1 (OFFL):  out = (A+A2)@[B0|B1] + [bias0|bias1] -> fp32 (Mrows,96).
// ---------------------------------------------------------------------------
template <int NC, int MT, int MR, int MODE>
__device__ __forceinline__ void gemm_body(
    const float* __restrict__ A, const float* __restrict__ A2,
    const float* __restrict__ B0, const float* __restrict__ B1,
    const float* __restrict__ bias0, const float* __restrict__ bias1,
    float* __restrict__ outf, char* __restrict__ out8,
    int Mrows, int m0, int tid, int nthreads, float (*Alds)[132]) {
  constexpr int NTHR = (NC / 4) * (MT / MR);

  for (int i = tid; i < MT * 32; i += nthreads) {
    int r = i >> 5, k = (i & 31) * 4;
    int row = m0 + r;
    float4 v = make_float4(0.f, 0.f, 0.f, 0.f);
    if (row < Mrows) {
      v = *(const float4*)(A + (size_t)row * C_ + k);
      if (MODE == 1) {
        float4 v2 = *(const float4*)(A2 + (size_t)row * C_ + k);
        v.x += v2.x; v.y += v2.y; v.z += v2.z; v.w += v2.w;
      }
    }
    *(float4*)(&Alds[r][k]) = v;
  }
  __syncthreads();
  if (tid >= NTHR) return;

  int ci = tid % (NC / 4);
  int mi = tid / (NC / 4);
  int c0 = ci * 4, r0 = mi * MR;

  const float* bs;
  if (MODE == 1) bs = (c0 < 64) ? bias0 + c0 : bias1 + (c0 - 64);
  else bs = bias0 + c0;

  float acc[MR][4];
#pragma unroll
  for (int j = 0; j < MR; ++j)
#pragma unroll
    for (int cc = 0; cc < 4; ++cc) acc[j][cc] = bs[cc];

#pragma unroll 2
  for (int k4 = 0; k4 < C_; k4 += 4) {
    float bf[16];
#pragma unroll
    for (int kk = 0; kk < 4; ++kk) {
      int k = k4 + kk;
      float4 b4;
      if (MODE == 1)
        b4 = (c0 < 64) ? *(const float4*)(B0 + (size_t)k * 64 + c0)
                       : *(const float4*)(B1 + (size_t)k * 32 + (c0 - 64));
      else
        b4 = *(const float4*)(B0 + (size_t)k * NC + c0);
      bf[kk * 4 + 0] = b4.x; bf[kk * 4 + 1] = b4.y;
      bf[kk * 4 + 2] = b4.z; bf[kk * 4 + 3] = b4.w;
    }
    float af[MR * 4];
#pragma unroll
    for (int j = 0; j < MR; ++j) {
      float4 a4 = *(const float4*)(&Alds[r0 + j][k4]);
      af[j * 4 + 0] = a4.x; af[j * 4 + 1] = a4.y;
      af[j * 4 + 2] = a4.z; af[j * 4 + 3] = a4.w;
    }
#pragma unroll
    for (int j = 0; j < MR; ++j)
#pragma unroll
      for (int kk = 0; kk < 4; ++kk)
#pragma unroll
        for (int cc = 0; cc < 4; ++cc)
          acc[j][cc] = fmaf(af[j * 4 + kk], bf[kk * 4 + cc], acc[j][cc]);
  }

#pragma unroll
  for (int j = 0; j < MR; ++j) {
    int row = m0 + r0 + j;
    if (row >= Mrows) continue;
    if (MODE == 0) {
      int s = row / M_, mm = row % M_;
      int y = mm / WF_, x = mm % WF_;
      int h = c0 >> 5, d0 = c0 & 31;
      int w = __builtin_amdgcn_cvt_pk_fp8_f32(acc[j][0], acc[j][1], 0, false);
      w = __builtin_amdgcn_cvt_pk_fp8_f32(acc[j][2], acc[j][3], w, true);
      size_t hm = (size_t)s * H_ + h;
      *(int*)(out8 + (hm * M_ + mm) * 32 + d0) = w;       // copy A
      if (x > 0) {                                        // copy B
        int kp = (x - 1) >> 1, slot = 1 - (x & 1);
        *(int*)(out8 + ABYTES + ((hm * HF_ + y) * 25 + kp) * 64 +
                slot * 32 + d0) = w;
      }
    } else if (MODE == 1) {
      *(float4*)(outf + (size_t)row * 96 + c0) =
          make_float4(acc[j][0], acc[j][1], acc[j][2], acc[j][3]);
    }
  }
}

// ---------------------------------------------------------------------------
__global__ __launch_bounds__(256) void prep_kernel(
    const float* __restrict__ value, const float* __restrict__ w_val,
    const float* __restrict__ b_val, char* __restrict__ vh8,
    const float* __restrict__ query, const float* __restrict__ query_pos,
    const float* __restrict__ w_off, const float* __restrict__ b_off,
    const float* __restrict__ w_attn, const float* __restrict__ b_attn,
    float* __restrict__ OFFL) {
  __shared__ float Alds[32][132];
  int bid = blockIdx.x;
  if (bid < NB_V) {
    gemm_body<128, 32, 4, 0>(value, nullptr, w_val, nullptr, b_val, nullptr,
                             nullptr, vh8, SM_, bid * 32, threadIdx.x, 256,
                             Alds);
  } else {
    gemm_body<96, 32, 4, 1>(query, query_pos, w_off, w_attn, b_off, b_attn,
                            OFFL, nullptr, N_, (bid - NB_V) * 32, threadIdx.x,
                            256, Alds);
  }
}

// ---------------------------------------------------------------------------
// Fused deformable sampling + output projection. QB_=8 queries / 256 threads.
// Gather: branch-free 48-sample loop; per sample: 1 ds_read_b64 (idx pair) +
// 1 ds_read_b32 (fp16x2 weight picked by x-half) + 2 saddr dwordx2 loads
// (64-B aligned spans via parity-dual fp8 layout = exactly 2 lines/sample).
// Accumulation in floatx2 -> v_pk_fma_f32 (8 packed FMA/sample, not 16
// scalar). sl overlays dead stage arrays (LDS ~30.7 KB, 5 blocks/CU).
// ---------------------------------------------------------------------------
__global__ __launch_bounds__(256) void attn2_kernel(
    const float* __restrict__ OFFL,     // (N,96): [0:64)=off, [64:96)=logits
    const float* __restrict__ refpts,   // (S,1,N,D,2)
    const int*   __restrict__ bev_mask, // (S,1,N,D)
    const char*  __restrict__ wsbase,   // d_ws base; value data at +64 (dual)
    const float* __restrict__ query,    // (N,128)
    const float* __restrict__ w_out,    // (128,128)
    const float* __restrict__ b_out,    // (128)
    float* __restrict__ out) {          // (N,128)
  int n0 = blockIdx.x * QB_;
  int tid = threadIdx.x;

  // ---- manual LDS layout (~30 KB) ----------------------------------------
  __shared__ char smem[30656];
  int2*   sidx  = (int2*)smem;                       // [q*194+j] 12416 B
  half2v* swh   = (half2v*)(smem + 12416);           // [(q*194+j)*2+half]
  float*  offp  = (float*)(smem + 24832);            // [q*64+c]  2048 B
  float*  logtp = (float*)(smem + 24832 + 2048);     // [q*32+j]  1024 B
  float*  awp   = (float*)(smem + 24832 + 3072);     // [q*32+j]  1024 B
  float*  reflp = (float*)(smem + 24832 + 4096);     // [q*48+r]  1536 B
  float*  slp   = (float*)(smem + 24832);            // [q*132+k] overlays
  int*    smaskp= (int*)(smem + 30464);              // [q*6+s]   192 B

  // ---- stage -------------------------------------------------------------
  for (int i = tid; i < QB_ * 96; i += 256) {
    int q = i / 96, c = i % 96;
    float v = OFFL[(size_t)(n0 + q) * 96 + c];
    if (c < 64) offp[q * 64 + c] = v; else logtp[q * 32 + c - 64] = v;
  }
  for (int i = tid; i < QB_ * 48; i += 256) {
    int q = i / 48, rem = i % 48;
    int s = rem >> 3, r8 = rem & 7;
    reflp[q * 48 + rem] = refpts[((size_t)s * N_ + (n0 + q)) * 8 + r8];
  }
  if (tid < QB_ * 6) {
    int q = tid / 6, s = tid % 6;
    const int* bm = bev_mask + ((size_t)s * N_ + (n0 + q)) * D_;
    smaskp[tid] = (bm[0] | bm[1] | bm[2] | bm[3]) ? 1 : 0;
  }
  __syncthreads();

  // ---- softmax over P per head -------------------------------------------
  {
    int q = tid >> 5, j = tid & 31, h = j >> 3;
    float mx = -1e30f;
#pragma unroll
    for (int p = 0; p < P_; ++p) mx = fmaxf(mx, logtp[q * 32 + h * P_ + p]);
    float sum = 0.f;
#pragma unroll
    for (int p = 0; p < P_; ++p) sum += expf(logtp[q * 32 + h * P_ + p] - mx);
    awp[q * 32 + j] = expf(logtp[q * 32 + j] - mx) / sum;
  }
  __syncthreads();

  // ---- per-sample params: j = s*32 + p*4 + h; smask folded into weights --
  for (int i = tid; i < QB_ * 192; i += 256) {
    int q = i / 192, j = i % 192;
    int s = j >> 5, w32 = j & 31, p = w32 >> 2, h = w32 & 3;
    int pd = p >> 2, dd = p & 3;
    float rx = reflp[q * 48 + s * 8 + dd * 2 + 0];
    float ry = reflp[q * 48 + s * 8 + dd * 2 + 1];
    float ox = offp[q * 64 + h * 16 + pd * 8 + dd * 2 + 0];
    float oy = offp[q * 64 + h * 16 + pd * 8 + dd * 2 + 1];
    float ix = rx * (float)WF_ + ox - 0.5f;
    float iy = ry * (float)HF_ + oy - 0.5f;
    float x0f = floorf(ix), y0f = floorf(iy);
    int x0 = (int)x0f, y0 = (int)y0f;
    float wx1 = ix - x0f, wy1 = iy - y0f;
    float wx0 = 1.f - wx1, wy0 = 1.f - wy1;
    float a = awp[q * 32 + h * P_ + p] * (float)smaskp[q * 6 + s];
    bool vx0 = (x0 >= 0) && (x0 < WF_);
    bool vx1 = (x0 + 1 >= 0) && (x0 + 1 < WF_);
    bool vy0 = (y0 >= 0) && (y0 < HF_);
    bool vy1 = (y0 + 1 >= 0) && (y0 + 1 < HF_);
    int y0c = min(max(y0, 0), HF_ - 1);
    int y1c = min(max(y0 + 1, 0), HF_ - 1);
    int hm = s * H_ + h;
    int itop, ibot;
    if (x0 >= 0 && x0 <= WF_ - 2 && !(x0 & 1)) {
      itop = (hm * M_ + y0c * WF_ + x0) * 32;        // copy A, aligned
      ibot = (hm * M_ + y1c * WF_ + x0) * 32;
    } else if (x0 >= 1 && x0 <= WF_ - 1 && (x0 & 1)) {
      int kp = (x0 - 1) >> 1;                        // copy B, aligned
      itop = ABYTES + ((hm * HF_ + y0c) * 25 + kp) * 64;
      ibot = ABYTES + ((hm * HF_ + y1c) * 25 + kp) * 64;
    } else if (x0 == -1) {
      itop = (hm * M_ + y0c * WF_) * 32 - 32;        // guard-backed
      ibot = (hm * M_ + y1c * WF_) * 32 - 32;
    } else {
      itop = ibot = 0;  // all weights 0
    }
    float w00 = (vx0 && vy0) ? wx0 * wy0 * a : 0.f;
    float w10 = (vx1 && vy0) ? wx1 * wy0 * a : 0.f;
    float w01 = (vx0 && vy1) ? wx0 * wy1 * a : 0.f;
    float w11 = (vx1 && vy1) ? wx1 * wy1 * a : 0.f;
    sidx[q * 194 + j] = make_int2(itop + 64, ibot + 64);
    half2v lo = {(_Float16)w00, (_Float16)w01};  // x0 half: (top, bottom)
    half2v hi = {(_Float16)w10, (_Float16)w11};  // x0+1 half
    swh[(q * 194 + j) * 2 + 0] = lo;
    swh[(q * 194 + j) * 2 + 1] = hi;
  }
  __syncthreads();

  // ---- gather: branch-free, floatx2 (v_pk_fma_f32) accumulation ----------
  {
    int q = tid >> 5, t = tid & 31, h = t >> 3, c8 = t & 7;
    int hisel = (c8 >> 2) & 1;
    int lanebyte = c8 * 8;
    const int2* sx = sidx + q * 194;
    const half2v* swq = swh + (q * 194) * 2 + hisel;
    floatx2 a01 = {0.f, 0.f}, a23 = {0.f, 0.f};
    floatx2 a45 = {0.f, 0.f}, a67 = {0.f, 0.f};
#pragma unroll 4
    for (int u = 0; u < 48; ++u) {
      int j = (u >> 3) * 32 + (u & 7) * 4 + h;
      int2 I = sx[j];
      half2v w2 = swq[j * 2];
      floatx2 wt = {(float)w2[0], (float)w2[0]};
      floatx2 wb = {(float)w2[1], (float)w2[1]};
      int2 ta = *(const int2*)(wsbase + (I.x + lanebyte));
      int2 tb = *(const int2*)(wsbase + (I.y + lanebyte));
      a01 += __builtin_amdgcn_cvt_pk_f32_fp8(ta.x, false) * wt;
      a23 += __builtin_amdgcn_cvt_pk_f32_fp8(ta.x, true)  * wt;
      a45 += __builtin_amdgcn_cvt_pk_f32_fp8(ta.y, false) * wt;
      a67 += __builtin_amdgcn_cvt_pk_f32_fp8(ta.y, true)  * wt;
      a01 += __builtin_amdgcn_cvt_pk_f32_fp8(tb.x, false) * wb;
      a23 += __builtin_amdgcn_cvt_pk_f32_fp8(tb.x, true)  * wb;
      a45 += __builtin_amdgcn_cvt_pk_f32_fp8(tb.y, false) * wb;
      a67 += __builtin_amdgcn_cvt_pk_f32_fp8(tb.y, true)  * wb;
    }
    float av[8] = {a01[0], a01[1], a23[0], a23[1],
                   a45[0], a45[1], a67[0], a67[1]};
    // fold x-pair halves: lanes c8 and c8^4 hold the same channels
#pragma unroll
    for (int k = 0; k < 8; ++k) av[k] += __shfl_xor(av[k], 4);

    int cnt = smaskp[q * 6 + 0] + smaskp[q * 6 + 1] + smaskp[q * 6 + 2] +
              smaskp[q * 6 + 3] + smaskp[q * 6 + 4] + smaskp[q * 6 + 5];
    float inv = 1.f / (float)(cnt > 0 ? cnt : 1);
    __syncthreads();  // all reads of sidx/swh done before sl overlay write
    if (!hisel) {
      float* dst = &slp[q * 132 + h * DH_ + (c8 & 3) * 8];
#pragma unroll
      for (int k = 0; k < 8; ++k) dst[k] = av[k] * inv;
    }
  }
  __syncthreads();

  // ---- tiled output projection: out = sl@w_out + b_out + query -----------
  {
    int q2 = tid >> 5, c0 = (tid & 31) * 4;
    int n = n0 + q2;
    float4 qv = *(const float4*)(query + (size_t)n * C_ + c0);
    float4 bv = *(const float4*)(b_out + c0);
    floatx2 r01 = {bv.x + qv.x, bv.y + qv.y};
    floatx2 r23 = {bv.z + qv.z, bv.w + qv.w};
#pragma unroll 4
    for (int k = 0; k < C_; ++k) {
      floatx2 a = {slp[q2 * 132 + k], slp[q2 * 132 + k]};
      float4 w4 = *(const float4*)(w_out + (size_t)k * C_ + c0);
      floatx2 w01 = {w4.x, w4.y}, w23 = {w4.z, w4.w};
      r01 += a * w01;
      r23 += a * w23;
    }
    *(float4*)(out + (size_t)n * C_ + c0) =
        make_float4(r01[0], r01[1], r23[0], r23[1]);
  }
}

// ---------------------------------------------------------------------------
extern "C" void kernel_launch(void* const* d_in, const int* in_sizes, int n_in,
                              void* d_out, int out_size, void* d_ws, size_t ws_size,
                              hipStream_t stream) {
  const float* query     = (const float*)d_in[0];
  const float* value     = (const float*)d_in[2];
  const float* query_pos = (const float*)d_in[3];
  const float* refpts    = (const float*)d_in[4];
  const int*   bev_mask  = (const int*)d_in[5];
  const float* w_off     = (const float*)d_in[6];
  const float* b_off     = (const float*)d_in[7];
  const float* w_attn    = (const float*)d_in[8];
  const float* b_attn    = (const float*)d_in[9];
  const float* w_val     = (const float*)d_in[10];
  const float* b_val     = (const float*)d_in[11];
  const float* w_out     = (const float*)d_in[12];
  const float* b_out     = (const float*)d_in[13];

  char* ws = (char*)d_ws;
  char* vh8   = ws + 64;                   // dual copies: 2*ABYTES = 2,150,400
  float* OFFL = (float*)(ws + 64 + 2 * (size_t)ABYTES + 64);   // 3,840,000 B

  prep_kernel<<<NB_V + NB_O, 256, 0, stream>>>(
      value, w_val, b_val, vh8, query, query_pos, w_off, b_off, w_attn, b_attn,
      OFFL);
  attn2_kernel<<<N_ / QB_, 256, 0, stream>>>(OFFL, refpts, bev_mask, ws,
                                             query, w_out, b_out,
                                             (float*)d_out);
}

// Round 13
// 154.158 us; speedup vs baseline: 1.0297x; 1.0044x over previous
//
#include <hip/hip_runtime.h>
#include <math.h>

#define S_ 6
#define N_ 10000
#define C_ 128
#define D_ 4
#define H_ 4
#define P_ 8
#define HF_ 28
#define WF_ 50
#define M_ (HF_ * WF_)   // 1400
#define DH_ 32
#define SM_ (S_ * M_)    // 8400
#define QB_ 8            // queries per attn block (256 threads)
// one fp8 value-copy: S*H*M pixels x 32 B = 1,075,200 B
#define ABYTES (S_ * H_ * M_ * 32)

#define NB_V ((SM_ + 31) / 32)   // 263 vproj blocks
#define NB_O ((N_ + 31) / 32)    // 313 OFFL blocks

typedef float floatx2 __attribute__((ext_vector_type(2)));
typedef _Float16 half4h __attribute__((ext_vector_type(4)));

// ---------------------------------------------------------------------------
// Shared GEMM body, K=128, MRx4 micro-tile, k-blocked by 4 with ds_read_b128.
//   MODE 0 (vproj): out = A@B0 + bias0 -> fp8 e4m3, DUAL layout (A/B parity).
//   MODE 1 (OFFL):  out = (A+A2)@[B0|B1] + [bias0|bias1] -> fp32 (Mrows,96).
// ---------------------------------------------------------------------------
template <int NC, int MT, int MR, int MODE>
__device__ __forceinline__ void gemm_body(
    const float* __restrict__ A, const float* __restrict__ A2,
    const float* __restrict__ B0, const float* __restrict__ B1,
    const float* __restrict__ bias0, const float* __restrict__ bias1,
    float* __restrict__ outf, char* __restrict__ out8,
    int Mrows, int m0, int tid, int nthreads, float (*Alds)[132]) {
  constexpr int NTHR = (NC / 4) * (MT / MR);

  for (int i = tid; i < MT * 32; i += nthreads) {
    int r = i >> 5, k = (i & 31) * 4;
    int row = m0 + r;
    float4 v = make_float4(0.f, 0.f, 0.f, 0.f);
    if (row < Mrows) {
      v = *(const float4*)(A + (size_t)row * C_ + k);
      if (MODE == 1) {
        float4 v2 = *(const float4*)(A2 + (size_t)row * C_ + k);
        v.x += v2.x; v.y += v2.y; v.z += v2.z; v.w += v2.w;
      }
    }
    *(float4*)(&Alds[r][k]) = v;
  }
  __syncthreads();
  if (tid >= NTHR) return;

  int ci = tid % (NC / 4);
  int mi = tid / (NC / 4);
  int c0 = ci * 4, r0 = mi * MR;

  const float* bs;
  if (MODE == 1) bs = (c0 < 64) ? bias0 + c0 : bias1 + (c0 - 64);
  else bs = bias0 + c0;

  float acc[MR][4];
#pragma unroll
  for (int j = 0; j < MR; ++j)
#pragma unroll
    for (int cc = 0; cc < 4; ++cc) acc[j][cc] = bs[cc];

#pragma unroll 2
  for (int k4 = 0; k4 < C_; k4 += 4) {
    float bf[16];
#pragma unroll
    for (int kk = 0; kk < 4; ++kk) {
      int k = k4 + kk;
      float4 b4;
      if (MODE == 1)
        b4 = (c0 < 64) ? *(const float4*)(B0 + (size_t)k * 64 + c0)
                       : *(const float4*)(B1 + (size_t)k * 32 + (c0 - 64));
      else
        b4 = *(const float4*)(B0 + (size_t)k * NC + c0);
      bf[kk * 4 + 0] = b4.x; bf[kk * 4 + 1] = b4.y;
      bf[kk * 4 + 2] = b4.z; bf[kk * 4 + 3] = b4.w;
    }
    float af[MR * 4];
#pragma unroll
    for (int j = 0; j < MR; ++j) {
      float4 a4 = *(const float4*)(&Alds[r0 + j][k4]);
      af[j * 4 + 0] = a4.x; af[j * 4 + 1] = a4.y;
      af[j * 4 + 2] = a4.z; af[j * 4 + 3] = a4.w;
    }
#pragma unroll
    for (int j = 0; j < MR; ++j)
#pragma unroll
      for (int kk = 0; kk < 4; ++kk)
#pragma unroll
        for (int cc = 0; cc < 4; ++cc)
          acc[j][cc] = fmaf(af[j * 4 + kk], bf[kk * 4 + cc], acc[j][cc]);
  }

#pragma unroll
  for (int j = 0; j < MR; ++j) {
    int row = m0 + r0 + j;
    if (row >= Mrows) continue;
    if (MODE == 0) {
      int s = row / M_, mm = row % M_;
      int y = mm / WF_, x = mm % WF_;
      int h = c0 >> 5, d0 = c0 & 31;
      int w = __builtin_amdgcn_cvt_pk_fp8_f32(acc[j][0], acc[j][1], 0, false);
      w = __builtin_amdgcn_cvt_pk_fp8_f32(acc[j][2], acc[j][3], w, true);
      size_t hm = (size_t)s * H_ + h;
      *(int*)(out8 + (hm * M_ + mm) * 32 + d0) = w;       // copy A
      if (x > 0) {                                        // copy B
        int kp = (x - 1) >> 1, slot = 1 - (x & 1);
        *(int*)(out8 + ABYTES + ((hm * HF_ + y) * 25 + kp) * 64 +
                slot * 32 + d0) = w;
      }
    } else if (MODE == 1) {
      *(float4*)(outf + (size_t)row * 96 + c0) =
          make_float4(acc[j][0], acc[j][1], acc[j][2], acc[j][3]);
    }
  }
}

// ---------------------------------------------------------------------------
__global__ __launch_bounds__(256) void prep_kernel(
    const float* __restrict__ value, const float* __restrict__ w_val,
    const float* __restrict__ b_val, char* __restrict__ vh8,
    const float* __restrict__ query, const float* __restrict__ query_pos,
    const float* __restrict__ w_off, const float* __restrict__ b_off,
    const float* __restrict__ w_attn, const float* __restrict__ b_attn,
    float* __restrict__ OFFL) {
  __shared__ float Alds[32][132];
  int bid = blockIdx.x;
  if (bid < NB_V) {
    gemm_body<128, 32, 4, 0>(value, nullptr, w_val, nullptr, b_val, nullptr,
                             nullptr, vh8, SM_, bid * 32, threadIdx.x, 256,
                             Alds);
  } else {
    gemm_body<96, 32, 4, 1>(query, query_pos, w_off, w_attn, b_off, b_attn,
                            OFFL, nullptr, N_, (bid - NB_V) * 32, threadIdx.x,
                            256, Alds);
  }
}

// ---------------------------------------------------------------------------
// Fused deformable sampling + output projection. QB_=8 queries / 256 threads.
// Role-split gather: lane c8 = rowsel(top/bot) x xsel(x0/x1) x chalf(16ch):
// per sample per lane = 1 ds_read_b32 (its span offset) + 1 ds_read_u16
// (its weight) + ONE global dwordx4 (16 B quarter-span) + 8 cvt + 8 pk_fma.
// Fold at end: shfl_xor(2) folds x, shfl_xor(4) folds rows. Exactly 2 cache
// lines/sample via parity-dual fp8 layout. sl overlays dead stage arrays.
// ---------------------------------------------------------------------------
__global__ __launch_bounds__(256) void attn2_kernel(
    const float* __restrict__ OFFL,     // (N,96): [0:64)=off, [64:96)=logits
    const float* __restrict__ refpts,   // (S,1,N,D,2)
    const int*   __restrict__ bev_mask, // (S,1,N,D)
    const char*  __restrict__ wsbase,   // d_ws base; value data at +64 (dual)
    const float* __restrict__ query,    // (N,128)
    const float* __restrict__ w_out,    // (128,128)
    const float* __restrict__ b_out,    // (128)
    float* __restrict__ out) {          // (N,128)
  int n0 = blockIdx.x * QB_;
  int tid = threadIdx.x;

  // ---- manual LDS layout (~30 KB) ----------------------------------------
  __shared__ char smem[30656];
  int2*   sidx  = (int2*)smem;                       // [q*194+j] 12416 B
  half4h* swh   = (half4h*)(smem + 12416);           // [q*194+j] 12416 B
  float*  offp  = (float*)(smem + 24832);            // [q*64+c]  2048 B
  float*  logtp = (float*)(smem + 24832 + 2048);     // [q*32+j]  1024 B
  float*  awp   = (float*)(smem + 24832 + 3072);     // [q*32+j]  1024 B
  float*  reflp = (float*)(smem + 24832 + 4096);     // [q*48+r]  1536 B
  float*  slp   = (float*)(smem + 24832);            // [q*132+k] overlays
  int*    smaskp= (int*)(smem + 30464);              // [q*6+s]   192 B

  // ---- stage -------------------------------------------------------------
  for (int i = tid; i < QB_ * 96; i += 256) {
    int q = i / 96, c = i % 96;
    float v = OFFL[(size_t)(n0 + q) * 96 + c];
    if (c < 64) offp[q * 64 + c] = v; else logtp[q * 32 + c - 64] = v;
  }
  for (int i = tid; i < QB_ * 48; i += 256) {
    int q = i / 48, rem = i % 48;
    int s = rem >> 3, r8 = rem & 7;
    reflp[q * 48 + rem] = refpts[((size_t)s * N_ + (n0 + q)) * 8 + r8];
  }
  if (tid < QB_ * 6) {
    int q = tid / 6, s = tid % 6;
    const int* bm = bev_mask + ((size_t)s * N_ + (n0 + q)) * D_;
    smaskp[tid] = (bm[0] | bm[1] | bm[2] | bm[3]) ? 1 : 0;
  }
  __syncthreads();

  // ---- softmax over P per head -------------------------------------------
  {
    int q = tid >> 5, j = tid & 31, h = j >> 3;
    float mx = -1e30f;
#pragma unroll
    for (int p = 0; p < P_; ++p) mx = fmaxf(mx, logtp[q * 32 + h * P_ + p]);
    float sum = 0.f;
#pragma unroll
    for (int p = 0; p < P_; ++p) sum += expf(logtp[q * 32 + h * P_ + p] - mx);
    awp[q * 32 + j] = expf(logtp[q * 32 + j] - mx) / sum;
  }
  __syncthreads();

  // ---- per-sample params: j = s*32 + p*4 + h; smask folded into weights --
  for (int i = tid; i < QB_ * 192; i += 256) {
    int q = i / 192, j = i % 192;
    int s = j >> 5, w32 = j & 31, p = w32 >> 2, h = w32 & 3;
    int pd = p >> 2, dd = p & 3;
    float rx = reflp[q * 48 + s * 8 + dd * 2 + 0];
    float ry = reflp[q * 48 + s * 8 + dd * 2 + 1];
    float ox = offp[q * 64 + h * 16 + pd * 8 + dd * 2 + 0];
    float oy = offp[q * 64 + h * 16 + pd * 8 + dd * 2 + 1];
    float ix = rx * (float)WF_ + ox - 0.5f;
    float iy = ry * (float)HF_ + oy - 0.5f;
    float x0f = floorf(ix), y0f = floorf(iy);
    int x0 = (int)x0f, y0 = (int)y0f;
    float wx1 = ix - x0f, wy1 = iy - y0f;
    float wx0 = 1.f - wx1, wy0 = 1.f - wy1;
    float a = awp[q * 32 + h * P_ + p] * (float)smaskp[q * 6 + s];
    bool vx0 = (x0 >= 0) && (x0 < WF_);
    bool vx1 = (x0 + 1 >= 0) && (x0 + 1 < WF_);
    bool vy0 = (y0 >= 0) && (y0 < HF_);
    bool vy1 = (y0 + 1 >= 0) && (y0 + 1 < HF_);
    int y0c = min(max(y0, 0), HF_ - 1);
    int y1c = min(max(y0 + 1, 0), HF_ - 1);
    int hm = s * H_ + h;
    int itop, ibot;
    if (x0 >= 0 && x0 <= WF_ - 2 && !(x0 & 1)) {
      itop = (hm * M_ + y0c * WF_ + x0) * 32;        // copy A, aligned
      ibot = (hm * M_ + y1c * WF_ + x0) * 32;
    } else if (x0 >= 1 && x0 <= WF_ - 1 && (x0 & 1)) {
      int kp = (x0 - 1) >> 1;                        // copy B, aligned
      itop = ABYTES + ((hm * HF_ + y0c) * 25 + kp) * 64;
      ibot = ABYTES + ((hm * HF_ + y1c) * 25 + kp) * 64;
    } else if (x0 == -1) {
      itop = (hm * M_ + y0c * WF_) * 32 - 32;        // guard-backed
      ibot = (hm * M_ + y1c * WF_) * 32 - 32;
    } else {
      itop = ibot = 0;  // all weights 0
    }
    float w00 = (vx0 && vy0) ? wx0 * wy0 * a : 0.f;
    float w10 = (vx1 && vy0) ? wx1 * wy0 * a : 0.f;
    float w01 = (vx0 && vy1) ? wx0 * wy1 * a : 0.f;
    float w11 = (vx1 && vy1) ? wx1 * wy1 * a : 0.f;
    sidx[q * 194 + j] = make_int2(itop + 64, ibot + 64);
    // role order: [w00(x0,top), w10(x1,top), w01(x0,bot), w11(x1,bot)]
    half4h wv = {(_Float16)w00, (_Float16)w10, (_Float16)w01, (_Float16)w11};
    swh[q * 194 + j] = wv;
  }
  __syncthreads();

  // ---- gather: role-split, one dwordx4 per lane per sample ---------------
  {
    int q = tid >> 5, t = tid & 31, h = t >> 3, c8 = t & 7;
    int rowsel = (c8 >> 2) & 1;       // 0=top row, 1=bottom row
    int xsel   = (c8 >> 1) & 1;       // 0=x0, 1=x1
    int chalf  = c8 & 1;              // which 16 channels
    int role   = c8 >> 1;             // weight index (w00,w10,w01,w11)
    int lanebyte = xsel * 32 + chalf * 16;
    const int* sxi = (const int*)(sidx + q * 194);          // [j*2+rowsel]
    const _Float16* swq = (const _Float16*)(swh + q * 194); // [j*4+role]
    floatx2 acc[8] = {{0.f, 0.f}, {0.f, 0.f}, {0.f, 0.f}, {0.f, 0.f},
                      {0.f, 0.f}, {0.f, 0.f}, {0.f, 0.f}, {0.f, 0.f}};
#pragma unroll 8
    for (int u = 0; u < 48; ++u) {
      int j = (u >> 3) * 32 + (u & 7) * 4 + h;
      int off = sxi[j * 2 + rowsel];
      float w = (float)swq[j * 4 + role];
      floatx2 wv = {w, w};
      int4 tq = *(const int4*)(wsbase + (off + lanebyte));
      acc[0] += __builtin_amdgcn_cvt_pk_f32_fp8(tq.x, false) * wv;
      acc[1] += __builtin_amdgcn_cvt_pk_f32_fp8(tq.x, true)  * wv;
      acc[2] += __builtin_amdgcn_cvt_pk_f32_fp8(tq.y, false) * wv;
      acc[3] += __builtin_amdgcn_cvt_pk_f32_fp8(tq.y, true)  * wv;
      acc[4] += __builtin_amdgcn_cvt_pk_f32_fp8(tq.z, false) * wv;
      acc[5] += __builtin_amdgcn_cvt_pk_f32_fp8(tq.z, true)  * wv;
      acc[6] += __builtin_amdgcn_cvt_pk_f32_fp8(tq.w, false) * wv;
      acc[7] += __builtin_amdgcn_cvt_pk_f32_fp8(tq.w, true)  * wv;
    }
    float av[16];
#pragma unroll
    for (int k = 0; k < 8; ++k) { av[2 * k] = acc[k][0]; av[2 * k + 1] = acc[k][1]; }
    // fold x-halves (lanes differing in bit1), then rows (bit2)
#pragma unroll
    for (int k = 0; k < 16; ++k) av[k] += __shfl_xor(av[k], 2);
#pragma unroll
    for (int k = 0; k < 16; ++k) av[k] += __shfl_xor(av[k], 4);

    int cnt = smaskp[q * 6 + 0] + smaskp[q * 6 + 1] + smaskp[q * 6 + 2] +
              smaskp[q * 6 + 3] + smaskp[q * 6 + 4] + smaskp[q * 6 + 5];
    float inv = 1.f / (float)(cnt > 0 ? cnt : 1);
    if (c8 < 2) {  // lanes 0/1 hold the folded 16-ch halves of head h
      float* dst = &slp[q * 132 + h * DH_ + chalf * 16];
#pragma unroll
      for (int k = 0; k < 16; ++k) dst[k] = av[k] * inv;
    }
  }
  __syncthreads();

  // ---- tiled output projection: out = sl@w_out + b_out + query -----------
  {
    int q2 = tid >> 5, c0 = (tid & 31) * 4;
    int n = n0 + q2;
    float4 qv = *(const float4*)(query + (size_t)n * C_ + c0);
    float4 bv = *(const float4*)(b_out + c0);
    floatx2 r01 = {bv.x + qv.x, bv.y + qv.y};
    floatx2 r23 = {bv.z + qv.z, bv.w + qv.w};
#pragma unroll 4
    for (int k = 0; k < C_; ++k) {
      floatx2 a = {slp[q2 * 132 + k], slp[q2 * 132 + k]};
      float4 w4 = *(const float4*)(w_out + (size_t)k * C_ + c0);
      floatx2 w01 = {w4.x, w4.y}, w23 = {w4.z, w4.w};
      r01 += a * w01;
      r23 += a * w23;
    }
    *(float4*)(out + (size_t)n * C_ + c0) =
        make_float4(r01[0], r01[1], r23[0], r23[1]);
  }
}

// ---------------------------------------------------------------------------
extern "C" void kernel_launch(void* const* d_in, const int* in_sizes, int n_in,
                              void* d_out, int out_size, void* d_ws, size_t ws_size,
                              hipStream_t stream) {
  const float* query     = (const float*)d_in[0];
  const float* value     = (const float*)d_in[2];
  const float* query_pos = (const float*)d_in[3];
  const float* refpts    = (const float*)d_in[4];
  const int*   bev_mask  = (const int*)d_in[5];
  const float* w_off     = (const float*)d_in[6];
  const float* b_off     = (const float*)d_in[7];
  const float* w_attn    = (const float*)d_in[8];
  const float* b_attn    = (const float*)d_in[9];
  const float* w_val     = (const float*)d_in[10];
  const float* b_val     = (const float*)d_in[11];
  const float* w_out     = (const float*)d_in[12];
  const float* b_out     = (const float*)d_in[13];

  char* ws = (char*)d_ws;
  char* vh8   = ws + 64;                   // dual copies: 2*ABYTES = 2,150,400
  float* OFFL = (float*)(ws + 64 + 2 * (size_t)ABYTES + 64);   // 3,840,000 B

  prep_kernel<<<NB_V + NB_O, 256, 0, stream>>>(
      value, w_val, b_val, vh8, query, query_pos, w_off, b_off, w_attn, b_attn,
      OFFL);
  attn2_kernel<<<N_ / QB_, 256, 0, stream>>>(OFFL, refpts, bev_mask, ws,
                                             query, w_out, b_out,
                                             (float*)d_out);
}

// Round 14
// 150.215 us; speedup vs baseline: 1.0568x; 1.0262x over previous
//
#include <hip/hip_runtime.h>
#include <math.h>

#define S_ 6
#define N_ 10000
#define C_ 128
#define D_ 4
#define H_ 4
#define P_ 8
#define HF_ 28
#define WF_ 50
#define M_ (HF_ * WF_)   // 1400
#define DH_ 32
#define SM_ (S_ * M_)    // 8400
#define QB_ 8            // queries per attn block (256 threads)
// one fp8 value-copy: S*H*M pixels x 32 B = 1,075,200 B
#define ABYTES (S_ * H_ * M_ * 32)

#define NB_V ((SM_ + 31) / 32)   // 263 vproj blocks
#define NB_O ((N_ + 31) / 32)    // 313 OFFL blocks

typedef float floatx2 __attribute__((ext_vector_type(2)));
typedef _Float16 half4h __attribute__((ext_vector_type(4)));

// ---------------------------------------------------------------------------
// Shared GEMM body, K=128, MRx4 micro-tile, k-blocked by 4 with ds_read_b128.
//   MODE 0 (vproj): out = A@B0 + bias0 -> fp8 e4m3, DUAL layout (A/B parity).
//   MODE 1 (OFFL):  out = (A+A2)@[B0|B1] + [bias0|bias1] -> fp32 (Mrows,96).
// ---------------------------------------------------------------------------
template <int NC, int MT, int MR, int MODE>
__device__ __forceinline__ void gemm_body(
    const float* __restrict__ A, const float* __restrict__ A2,
    const float* __restrict__ B0, const float* __restrict__ B1,
    const float* __restrict__ bias0, const float* __restrict__ bias1,
    float* __restrict__ outf, char* __restrict__ out8,
    int Mrows, int m0, int tid, int nthreads, float (*Alds)[132]) {
  constexpr int NTHR = (NC / 4) * (MT / MR);

  for (int i = tid; i < MT * 32; i += nthreads) {
    int r = i >> 5, k = (i & 31) * 4;
    int row = m0 + r;
    float4 v = make_float4(0.f, 0.f, 0.f, 0.f);
    if (row < Mrows) {
      v = *(const float4*)(A + (size_t)row * C_ + k);
      if (MODE == 1) {
        float4 v2 = *(const float4*)(A2 + (size_t)row * C_ + k);
        v.x += v2.x; v.y += v2.y; v.z += v2.z; v.w += v2.w;
      }
    }
    *(float4*)(&Alds[r][k]) = v;
  }
  __syncthreads();
  if (tid >= NTHR) return;

  int ci = tid % (NC / 4);
  int mi = tid / (NC / 4);
  int c0 = ci * 4, r0 = mi * MR;

  const float* bs;
  if (MODE == 1) bs = (c0 < 64) ? bias0 + c0 : bias1 + (c0 - 64);
  else bs = bias0 + c0;

  float acc[MR][4];
#pragma unroll
  for (int j = 0; j < MR; ++j)
#pragma unroll
    for (int cc = 0; cc < 4; ++cc) acc[j][cc] = bs[cc];

#pragma unroll 2
  for (int k4 = 0; k4 < C_; k4 += 4) {
    float bf[16];
#pragma unroll
    for (int kk = 0; kk < 4; ++kk) {
      int k = k4 + kk;
      float4 b4;
      if (MODE == 1)
        b4 = (c0 < 64) ? *(const float4*)(B0 + (size_t)k * 64 + c0)
                       : *(const float4*)(B1 + (size_t)k * 32 + (c0 - 64));
      else
        b4 = *(const float4*)(B0 + (size_t)k * NC + c0);
      bf[kk * 4 + 0] = b4.x; bf[kk * 4 + 1] = b4.y;
      bf[kk * 4 + 2] = b4.z; bf[kk * 4 + 3] = b4.w;
    }
    float af[MR * 4];
#pragma unroll
    for (int j = 0; j < MR; ++j) {
      float4 a4 = *(const float4*)(&Alds[r0 + j][k4]);
      af[j * 4 + 0] = a4.x; af[j * 4 + 1] = a4.y;
      af[j * 4 + 2] = a4.z; af[j * 4 + 3] = a4.w;
    }
#pragma unroll
    for (int j = 0; j < MR; ++j)
#pragma unroll
      for (int kk = 0; kk < 4; ++kk)
#pragma unroll
        for (int cc = 0; cc < 4; ++cc)
          acc[j][cc] = fmaf(af[j * 4 + kk], bf[kk * 4 + cc], acc[j][cc]);
  }

#pragma unroll
  for (int j = 0; j < MR; ++j) {
    int row = m0 + r0 + j;
    if (row >= Mrows) continue;
    if (MODE == 0) {
      int s = row / M_, mm = row % M_;
      int y = mm / WF_, x = mm % WF_;
      int h = c0 >> 5, d0 = c0 & 31;
      int w = __builtin_amdgcn_cvt_pk_fp8_f32(acc[j][0], acc[j][1], 0, false);
      w = __builtin_amdgcn_cvt_pk_fp8_f32(acc[j][2], acc[j][3], w, true);
      size_t hm = (size_t)s * H_ + h;
      *(int*)(out8 + (hm * M_ + mm) * 32 + d0) = w;       // copy A
      if (x > 0) {                                        // copy B
        int kp = (x - 1) >> 1, slot = 1 - (x & 1);
        *(int*)(out8 + ABYTES + ((hm * HF_ + y) * 25 + kp) * 64 +
                slot * 32 + d0) = w;
      }
    } else if (MODE == 1) {
      *(float4*)(outf + (size_t)row * 96 + c0) =
          make_float4(acc[j][0], acc[j][1], acc[j][2], acc[j][3]);
    }
  }
}

// ---------------------------------------------------------------------------
__global__ __launch_bounds__(256) void prep_kernel(
    const float* __restrict__ value, const float* __restrict__ w_val,
    const float* __restrict__ b_val, char* __restrict__ vh8,
    const float* __restrict__ query, const float* __restrict__ query_pos,
    const float* __restrict__ w_off, const float* __restrict__ b_off,
    const float* __restrict__ w_attn, const float* __restrict__ b_attn,
    float* __restrict__ OFFL) {
  __shared__ float Alds[32][132];
  int bid = blockIdx.x;
  if (bid < NB_V) {
    gemm_body<128, 32, 4, 0>(value, nullptr, w_val, nullptr, b_val, nullptr,
                             nullptr, vh8, SM_, bid * 32, threadIdx.x, 256,
                             Alds);
  } else {
    gemm_body<96, 32, 4, 1>(query, query_pos, w_off, w_attn, b_off, b_attn,
                            OFFL, nullptr, N_, (bid - NB_V) * 32, threadIdx.x,
                            256, Alds);
  }
}

// ---------------------------------------------------------------------------
// Fused deformable sampling + output projection. QB_=8 queries / 256 threads.
// Role-split gather (lane = rowsel x xsel x chalf, one dwordx4/sample) with
// ALL 48 per-lane params preloaded into VGPRs before the loop: the gather
// loop has NO LDS dependency in its address chain (the R13 bottleneck).
// ---------------------------------------------------------------------------
__global__ __launch_bounds__(256) void attn2_kernel(
    const float* __restrict__ OFFL,     // (N,96): [0:64)=off, [64:96)=logits
    const float* __restrict__ refpts,   // (S,1,N,D,2)
    const int*   __restrict__ bev_mask, // (S,1,N,D)
    const char*  __restrict__ wsbase,   // d_ws base; value data at +64 (dual)
    const float* __restrict__ query,    // (N,128)
    const float* __restrict__ w_out,    // (128,128)
    const float* __restrict__ b_out,    // (128)
    float* __restrict__ out) {          // (N,128)
  int n0 = blockIdx.x * QB_;
  int tid = threadIdx.x;

  // ---- manual LDS layout (~30 KB) ----------------------------------------
  __shared__ char smem[30656];
  int2*   sidx  = (int2*)smem;                       // [q*194+j] 12416 B
  half4h* swh   = (half4h*)(smem + 12416);           // [q*194+j] 12416 B
  float*  offp  = (float*)(smem + 24832);            // [q*64+c]  2048 B
  float*  logtp = (float*)(smem + 24832 + 2048);     // [q*32+j]  1024 B
  float*  awp   = (float*)(smem + 24832 + 3072);     // [q*32+j]  1024 B
  float*  reflp = (float*)(smem + 24832 + 4096);     // [q*48+r]  1536 B
  float*  slp   = (float*)(smem + 24832);            // [q*132+k] overlays
  int*    smaskp= (int*)(smem + 30464);              // [q*6+s]   192 B

  // ---- stage -------------------------------------------------------------
  for (int i = tid; i < QB_ * 96; i += 256) {
    int q = i / 96, c = i % 96;
    float v = OFFL[(size_t)(n0 + q) * 96 + c];
    if (c < 64) offp[q * 64 + c] = v; else logtp[q * 32 + c - 64] = v;
  }
  for (int i = tid; i < QB_ * 48; i += 256) {
    int q = i / 48, rem = i % 48;
    int s = rem >> 3, r8 = rem & 7;
    reflp[q * 48 + rem] = refpts[((size_t)s * N_ + (n0 + q)) * 8 + r8];
  }
  if (tid < QB_ * 6) {
    int q = tid / 6, s = tid % 6;
    const int* bm = bev_mask + ((size_t)s * N_ + (n0 + q)) * D_;
    smaskp[tid] = (bm[0] | bm[1] | bm[2] | bm[3]) ? 1 : 0;
  }
  __syncthreads();

  // ---- softmax over P per head -------------------------------------------
  {
    int q = tid >> 5, j = tid & 31, h = j >> 3;
    float mx = -1e30f;
#pragma unroll
    for (int p = 0; p < P_; ++p) mx = fmaxf(mx, logtp[q * 32 + h * P_ + p]);
    float sum = 0.f;
#pragma unroll
    for (int p = 0; p < P_; ++p) sum += expf(logtp[q * 32 + h * P_ + p] - mx);
    awp[q * 32 + j] = expf(logtp[q * 32 + j] - mx) / sum;
  }
  __syncthreads();

  // ---- per-sample params: j = s*32 + p*4 + h; smask folded into weights --
  for (int i = tid; i < QB_ * 192; i += 256) {
    int q = i / 192, j = i % 192;
    int s = j >> 5, w32 = j & 31, p = w32 >> 2, h = w32 & 3;
    int pd = p >> 2, dd = p & 3;
    float rx = reflp[q * 48 + s * 8 + dd * 2 + 0];
    float ry = reflp[q * 48 + s * 8 + dd * 2 + 1];
    float ox = offp[q * 64 + h * 16 + pd * 8 + dd * 2 + 0];
    float oy = offp[q * 64 + h * 16 + pd * 8 + dd * 2 + 1];
    float ix = rx * (float)WF_ + ox - 0.5f;
    float iy = ry * (float)HF_ + oy - 0.5f;
    float x0f = floorf(ix), y0f = floorf(iy);
    int x0 = (int)x0f, y0 = (int)y0f;
    float wx1 = ix - x0f, wy1 = iy - y0f;
    float wx0 = 1.f - wx1, wy0 = 1.f - wy1;
    float a = awp[q * 32 + h * P_ + p] * (float)smaskp[q * 6 + s];
    bool vx0 = (x0 >= 0) && (x0 < WF_);
    bool vx1 = (x0 + 1 >= 0) && (x0 + 1 < WF_);
    bool vy0 = (y0 >= 0) && (y0 < HF_);
    bool vy1 = (y0 + 1 >= 0) && (y0 + 1 < HF_);
    int y0c = min(max(y0, 0), HF_ - 1);
    int y1c = min(max(y0 + 1, 0), HF_ - 1);
    int hm = s * H_ + h;
    int itop, ibot;
    if (x0 >= 0 && x0 <= WF_ - 2 && !(x0 & 1)) {
      itop = (hm * M_ + y0c * WF_ + x0) * 32;        // copy A, aligned
      ibot = (hm * M_ + y1c * WF_ + x0) * 32;
    } else if (x0 >= 1 && x0 <= WF_ - 1 && (x0 & 1)) {
      int kp = (x0 - 1) >> 1;                        // copy B, aligned
      itop = ABYTES + ((hm * HF_ + y0c) * 25 + kp) * 64;
      ibot = ABYTES + ((hm * HF_ + y1c) * 25 + kp) * 64;
    } else if (x0 == -1) {
      itop = (hm * M_ + y0c * WF_) * 32 - 32;        // guard-backed
      ibot = (hm * M_ + y1c * WF_) * 32 - 32;
    } else {
      itop = ibot = 0;  // all weights 0
    }
    float w00 = (vx0 && vy0) ? wx0 * wy0 * a : 0.f;
    float w10 = (vx1 && vy0) ? wx1 * wy0 * a : 0.f;
    float w01 = (vx0 && vy1) ? wx0 * wy1 * a : 0.f;
    float w11 = (vx1 && vy1) ? wx1 * wy1 * a : 0.f;
    sidx[q * 194 + j] = make_int2(itop + 64, ibot + 64);
    // role order: [w00(x0,top), w10(x1,top), w01(x0,bot), w11(x1,bot)]
    half4h wv = {(_Float16)w00, (_Float16)w10, (_Float16)w01, (_Float16)w11};
    swh[q * 194 + j] = wv;
  }
  __syncthreads();

  // ---- gather: params preloaded to VGPRs, loop has no LDS dependency -----
  {
    int q = tid >> 5, t = tid & 31, h = t >> 3, c8 = t & 7;
    int rowsel = (c8 >> 2) & 1;       // 0=top row, 1=bottom row
    int xsel   = (c8 >> 1) & 1;       // 0=x0, 1=x1
    int chalf  = c8 & 1;              // which 16 channels
    int role   = c8 >> 1;             // weight index (w00,w10,w01,w11)
    int lanebyte = xsel * 32 + chalf * 16;
    const int* sxi = (const int*)(sidx + q * 194);          // [j*2+rowsel]
    const _Float16* swq = (const _Float16*)(swh + q * 194); // [j*4+role]

    // preload: 48 offsets + 48 fp16 weights -> VGPRs (one lgkm drain)
    int offR[48];
    _Float16 wR[48];
#pragma unroll
    for (int u = 0; u < 48; ++u) {
      int j = (u >> 3) * 32 + (u & 7) * 4 + h;
      offR[u] = sxi[j * 2 + rowsel];
      wR[u] = swq[j * 4 + role];
    }

    floatx2 acc[8] = {{0.f, 0.f}, {0.f, 0.f}, {0.f, 0.f}, {0.f, 0.f},
                      {0.f, 0.f}, {0.f, 0.f}, {0.f, 0.f}, {0.f, 0.f}};
#pragma unroll
    for (int u = 0; u < 48; ++u) {
      float w = (float)wR[u];
      floatx2 wv = {w, w};
      int4 tq = *(const int4*)(wsbase + (offR[u] + lanebyte));
      acc[0] += __builtin_amdgcn_cvt_pk_f32_fp8(tq.x, false) * wv;
      acc[1] += __builtin_amdgcn_cvt_pk_f32_fp8(tq.x, true)  * wv;
      acc[2] += __builtin_amdgcn_cvt_pk_f32_fp8(tq.y, false) * wv;
      acc[3] += __builtin_amdgcn_cvt_pk_f32_fp8(tq.y, true)  * wv;
      acc[4] += __builtin_amdgcn_cvt_pk_f32_fp8(tq.z, false) * wv;
      acc[5] += __builtin_amdgcn_cvt_pk_f32_fp8(tq.z, true)  * wv;
      acc[6] += __builtin_amdgcn_cvt_pk_f32_fp8(tq.w, false) * wv;
      acc[7] += __builtin_amdgcn_cvt_pk_f32_fp8(tq.w, true)  * wv;
    }
    float av[16];
#pragma unroll
    for (int k = 0; k < 8; ++k) { av[2 * k] = acc[k][0]; av[2 * k + 1] = acc[k][1]; }
    // fold x-halves (lanes differing in bit1), then rows (bit2)
#pragma unroll
    for (int k = 0; k < 16; ++k) av[k] += __shfl_xor(av[k], 2);
#pragma unroll
    for (int k = 0; k < 16; ++k) av[k] += __shfl_xor(av[k], 4);

    int cnt = smaskp[q * 6 + 0] + smaskp[q * 6 + 1] + smaskp[q * 6 + 2] +
              smaskp[q * 6 + 3] + smaskp[q * 6 + 4] + smaskp[q * 6 + 5];
    float inv = 1.f / (float)(cnt > 0 ? cnt : 1);
    if (c8 < 2) {  // lanes 0/1 hold the folded 16-ch halves of head h
      float* dst = &slp[q * 132 + h * DH_ + chalf * 16];
#pragma unroll
      for (int k = 0; k < 16; ++k) dst[k] = av[k] * inv;
    }
  }
  __syncthreads();

  // ---- tiled output projection: out = sl@w_out + b_out + query -----------
  {
    int q2 = tid >> 5, c0 = (tid & 31) * 4;
    int n = n0 + q2;
    float4 qv = *(const float4*)(query + (size_t)n * C_ + c0);
    float4 bv = *(const float4*)(b_out + c0);
    floatx2 r01 = {bv.x + qv.x, bv.y + qv.y};
    floatx2 r23 = {bv.z + qv.z, bv.w + qv.w};
#pragma unroll 4
    for (int k = 0; k < C_; ++k) {
      floatx2 a = {slp[q2 * 132 + k], slp[q2 * 132 + k]};
      float4 w4 = *(const float4*)(w_out + (size_t)k * C_ + c0);
      floatx2 w01 = {w4.x, w4.y}, w23 = {w4.z, w4.w};
      r01 += a * w01;
      r23 += a * w23;
    }
    *(float4*)(out + (size_t)n * C_ + c0) =
        make_float4(r01[0], r01[1], r23[0], r23[1]);
  }
}

// ---------------------------------------------------------------------------
extern "C" void kernel_launch(void* const* d_in, const int* in_sizes, int n_in,
                              void* d_out, int out_size, void* d_ws, size_t ws_size,
                              hipStream_t stream) {
  const float* query     = (const float*)d_in[0];
  const float* value     = (const float*)d_in[2];
  const float* query_pos = (const float*)d_in[3];
  const float* refpts    = (const float*)d_in[4];
  const int*   bev_mask  = (const int*)d_in[5];
  const float* w_off     = (const float*)d_in[6];
  const float* b_off     = (const float*)d_in[7];
  const float* w_attn    = (const float*)d_in[8];
  const float* b_attn    = (const float*)d_in[9];
  const float* w_val     = (const float*)d_in[10];
  const float* b_val     = (const float*)d_in[11];
  const float* w_out     = (const float*)d_in[12];
  const float* b_out     = (const float*)d_in[13];

  char* ws = (char*)d_ws;
  char* vh8   = ws + 64;                   // dual copies: 2*ABYTES = 2,150,400
  float* OFFL = (float*)(ws + 64 + 2 * (size_t)ABYTES + 64);   // 3,840,000 B

  prep_kernel<<<NB_V + NB_O, 256, 0, stream>>>(
      value, w_val, b_val, vh8, query, query_pos, w_off, b_off, w_attn, b_attn,
      OFFL);
  attn2_kernel<<<N_ / QB_, 256, 0, stream>>>(OFFL, refpts, bev_mask, ws,
                                             query, w_out, b_out,
                                             (float*)d_out);
}